// Round 1
// baseline (435.799 us; speedup 1.0000x reference)
//
#include <hip/hip_runtime.h>

// GCN block: h1 = ReLU(Agg(x@W1)+b1); h2 = ReLU(Agg(h1@W2)+b2); out = BN(h2)
// Agg[n] = dis[n] * ( sum_{e: col=n} h[row_e]*dis[row_e] + h[n]*dis[n] )
// Strategy: fold dis[row] into GEMM epilogue; build CSR (by col) per launch
// to make aggregation a pure gather (no float atomics).

#define D 128

// ---------------- zero scratch ----------------
__global__ void k_zero(int* __restrict__ deg, float* __restrict__ sums, int N) {
    int i = blockIdx.x * blockDim.x + threadIdx.x;
    if (i < N) deg[i] = 0;
    if (i < 256) sums[i] = 0.0f;   // sums[128] ++ sumsq[128], contiguous
}

// ---------------- degree histogram ----------------
__global__ void k_hist(const int* __restrict__ col, int* __restrict__ deg, int E) {
    int e = blockIdx.x * blockDim.x + threadIdx.x;
    if (e < E) atomicAdd(&deg[col[e]], 1);
}

// ---------------- prefix scan (3 kernels) ----------------
__global__ void k_scan1(const int* __restrict__ deg, int* __restrict__ bsum, int N) {
    __shared__ int s[256];
    int tid = threadIdx.x;
    int i = blockIdx.x * 256 + tid;
    s[tid] = (i < N) ? deg[i] : 0;
    __syncthreads();
    for (int o = 128; o > 0; o >>= 1) {
        if (tid < o) s[tid] += s[tid + o];
        __syncthreads();
    }
    if (tid == 0) bsum[blockIdx.x] = s[0];
}

// single block, nb <= 256: exclusive scan of block sums
__global__ void k_scan2(int* __restrict__ bsum, int nb) {
    __shared__ int s[256];
    int tid = threadIdx.x;
    int v = (tid < nb) ? bsum[tid] : 0;
    s[tid] = v;
    __syncthreads();
    for (int o = 1; o < 256; o <<= 1) {
        int t = (tid >= o) ? s[tid - o] : 0;
        __syncthreads();
        s[tid] += t;
        __syncthreads();
    }
    if (tid < nb) bsum[tid] = tid ? s[tid - 1] : 0;
}

__global__ void k_scan3(const int* __restrict__ deg, const int* __restrict__ bsum,
                        int* __restrict__ offs, int* __restrict__ cursor,
                        float* __restrict__ dis, int N, int E) {
    __shared__ int s[256];
    int tid = threadIdx.x;
    int i = blockIdx.x * 256 + tid;
    int d = (i < N) ? deg[i] : 0;
    s[tid] = d;
    __syncthreads();
    for (int o = 1; o < 256; o <<= 1) {
        int t = (tid >= o) ? s[tid - o] : 0;
        __syncthreads();
        s[tid] += t;
        __syncthreads();
    }
    if (i < N) {
        int excl = (tid ? s[tid - 1] : 0) + bsum[blockIdx.x];
        offs[i] = excl;
        cursor[i] = excl;
        dis[i] = rsqrtf((float)d + 1.0f);
    }
    if (i == 0) offs[N] = E;
}

// ---------------- CSR fill ----------------
__global__ void k_fill(const int* __restrict__ row, const int* __restrict__ col,
                       int* __restrict__ cursor, int* __restrict__ csr, int E) {
    int e = blockIdx.x * blockDim.x + threadIdx.x;
    if (e < E) {
        int p = atomicAdd(&cursor[col[e]], 1);
        csr[p] = row[e];
    }
}

// ---------------- GEMM: out[r] = (X @ W)[r] * dis[r] ----------------
// Block: 64 rows x 128 cols. 256 threads; thread (ry,cx): 4 rows, 8 cols
// (cols cx*4 and cx*4+64 as two float4 groups -> conflict-free LDS + coalesced).
// W (64KB) + Xt (32KB) in LDS => 1 block/CU, 4 waves.
__global__ __launch_bounds__(256) void k_gemm_scale(
        const float* __restrict__ X, const float* __restrict__ W,
        const float* __restrict__ dis, float* __restrict__ out, int n) {
    __shared__ float Ws[D * D];
    __shared__ float Xt[D * 64];   // transposed: Xt[k*64 + r]
    int tid = threadIdx.x;

    // load W (row-major [k][c], used as-is)
    for (int i = tid; i < D * D / 4; i += 256) {
        ((float4*)Ws)[i] = ((const float4*)W)[i];
    }
    // load X tile transposed; lanes vary in r -> conflict-free LDS writes
    int row0 = blockIdx.x * 64;
    for (int i = tid; i < 64 * 32; i += 256) {
        int r = i & 63;
        int kc = (i >> 6) << 2;
        float4 v = {0.f, 0.f, 0.f, 0.f};
        if (row0 + r < n) v = *(const float4*)&X[(size_t)(row0 + r) * D + kc];
        Xt[(kc + 0) * 64 + r] = v.x;
        Xt[(kc + 1) * 64 + r] = v.y;
        Xt[(kc + 2) * 64 + r] = v.z;
        Xt[(kc + 3) * 64 + r] = v.w;
    }
    __syncthreads();

    int ry = tid >> 4;   // 0..15 -> rows ry*4 .. ry*4+3
    int cx = tid & 15;   // 0..15 -> cols cx*4..+3 and 64+cx*4..+3
    float acc[4][8];
#pragma unroll
    for (int i = 0; i < 4; i++)
#pragma unroll
        for (int j = 0; j < 8; j++) acc[i][j] = 0.f;

#pragma unroll 4
    for (int k = 0; k < D; k++) {
        float4 a  = *(const float4*)&Xt[k * 64 + ry * 4];
        float4 b0 = *(const float4*)&Ws[k * D + cx * 4];
        float4 b1 = *(const float4*)&Ws[k * D + 64 + cx * 4];
        float av[4] = {a.x, a.y, a.z, a.w};
        float bv[8] = {b0.x, b0.y, b0.z, b0.w, b1.x, b1.y, b1.z, b1.w};
#pragma unroll
        for (int i = 0; i < 4; i++)
#pragma unroll
            for (int j = 0; j < 8; j++) acc[i][j] += av[i] * bv[j];
    }

#pragma unroll
    for (int i = 0; i < 4; i++) {
        int r = row0 + ry * 4 + i;
        if (r < n) {
            float sc = dis[r];
            float4 o0 = {acc[i][0] * sc, acc[i][1] * sc, acc[i][2] * sc, acc[i][3] * sc};
            float4 o1 = {acc[i][4] * sc, acc[i][5] * sc, acc[i][6] * sc, acc[i][7] * sc};
            *(float4*)&out[(size_t)r * D + cx * 4] = o0;
            *(float4*)&out[(size_t)r * D + 64 + cx * 4] = o1;
        }
    }
}

// ---------------- aggregation: y[n] = ReLU(dis[n]*(sum_e hs[src] + hs[n]) + b) ----------------
// hs rows are pre-scaled by dis[src]. One wave (64 lanes x float2) per node.
__global__ __launch_bounds__(256) void k_agg(
        const float* __restrict__ hs, const int* __restrict__ csr,
        const int* __restrict__ offs, const float* __restrict__ dis,
        const float* __restrict__ bias, float* __restrict__ out, int N) {
    int node = blockIdx.x * 4 + (threadIdx.x >> 6);
    if (node >= N) return;
    int lane = threadIdx.x & 63;
    int c = lane * 2;

    float2 acc = *(const float2*)&hs[(size_t)node * D + c];  // self term (pre-scaled)
    int e0 = offs[node], e1 = offs[node + 1];
    for (int e = e0; e < e1; e++) {
        int s = csr[e];
        float2 v = *(const float2*)&hs[(size_t)s * D + c];
        acc.x += v.x;
        acc.y += v.y;
    }
    float dn = dis[node];
    float2 b = *(const float2*)&bias[c];
    float ox = fmaxf(dn * acc.x + b.x, 0.0f);
    float oy = fmaxf(dn * acc.y + b.y, 0.0f);
    float2 o = {ox, oy};
    *(float2*)&out[(size_t)node * D + c] = o;
}

// ---------------- BN stats: per-feature sum & sumsq ----------------
__global__ void k_stats(const float* __restrict__ z, float* __restrict__ sums, int N) {
    int t = threadIdx.x;  // 0..127 = feature
    float s = 0.f, s2 = 0.f;
    for (int n = blockIdx.x; n < N; n += gridDim.x) {
        float v = z[(size_t)n * D + t];
        s += v;
        s2 += v * v;
    }
    atomicAdd(&sums[t], s);
    atomicAdd(&sums[D + t], s2);
}

// ---------------- BN normalize ----------------
__global__ void k_bn(const float* __restrict__ z, const float* __restrict__ sums,
                     const float* __restrict__ gamma, const float* __restrict__ beta,
                     float* __restrict__ out, int N) {
    int i = blockIdx.x * blockDim.x + threadIdx.x;  // float4 index
    int total = N * (D / 4);
    if (i >= total) return;
    int c4 = (i & (D / 4 - 1)) << 2;
    float4 s  = *(const float4*)&sums[c4];
    float4 s2 = *(const float4*)&sums[D + c4];
    float4 g  = *(const float4*)&gamma[c4];
    float4 b  = *(const float4*)&beta[c4];
    float4 v  = *(const float4*)&z[(size_t)i * 4];
    float invN = 1.0f / (float)N;
    float m0 = s.x * invN, m1 = s.y * invN, m2 = s.z * invN, m3 = s.w * invN;
    float i0 = rsqrtf(fmaxf(s2.x * invN - m0 * m0, 0.f) + 1e-5f);
    float i1 = rsqrtf(fmaxf(s2.y * invN - m1 * m1, 0.f) + 1e-5f);
    float i2 = rsqrtf(fmaxf(s2.z * invN - m2 * m2, 0.f) + 1e-5f);
    float i3 = rsqrtf(fmaxf(s2.w * invN - m3 * m3, 0.f) + 1e-5f);
    float4 o;
    o.x = g.x * (v.x - m0) * i0 + b.x;
    o.y = g.y * (v.y - m1) * i1 + b.y;
    o.z = g.z * (v.z - m2) * i2 + b.z;
    o.w = g.w * (v.w - m3) * i3 + b.w;
    *(float4*)&out[(size_t)i * 4] = o;
}

static inline size_t align_up(size_t x) { return (x + 1023) & ~(size_t)1023; }

extern "C" void kernel_launch(void* const* d_in, const int* in_sizes, int n_in,
                              void* d_out, int out_size, void* d_ws, size_t ws_size,
                              hipStream_t stream) {
    const float* x     = (const float*)d_in[0];
    const int*   ei    = (const int*)d_in[1];
    const float* W1    = (const float*)d_in[2];
    const float* b1    = (const float*)d_in[3];
    const float* W2    = (const float*)d_in[4];
    const float* b2    = (const float*)d_in[5];
    const float* gamma = (const float*)d_in[6];
    const float* beta  = (const float*)d_in[7];

    int N = in_sizes[0] / D;
    int E = in_sizes[1] / 2;
    const int* row = ei;
    const int* col = ei + E;

    char* p = (char*)d_ws;
    int* deg    = (int*)p;   p += align_up((size_t)N * 4);
    int* offs   = (int*)p;   p += align_up((size_t)(N + 1) * 4);
    int* cursor = (int*)p;   p += align_up((size_t)N * 4);
    int* bsum   = (int*)p;   p += align_up(256 * 4);
    float* dis  = (float*)p; p += align_up((size_t)N * 4);
    int* csr    = (int*)p;   p += align_up((size_t)E * 4);
    float* bufA = (float*)p; p += align_up((size_t)N * D * 4);
    float* bufB = (float*)p; p += align_up((size_t)N * D * 4);
    float* sums = (float*)p; p += align_up(256 * 4);

    int nb = (N + 255) / 256;   // 196 <= 256, fits single-block scan2

    k_zero<<<nb, 256, 0, stream>>>(deg, sums, N);
    k_hist<<<(E + 255) / 256, 256, 0, stream>>>(col, deg, E);
    k_scan1<<<nb, 256, 0, stream>>>(deg, bsum, N);
    k_scan2<<<1, 256, 0, stream>>>(bsum, nb);
    k_scan3<<<nb, 256, 0, stream>>>(deg, bsum, offs, cursor, dis, N, E);
    k_fill<<<(E + 255) / 256, 256, 0, stream>>>(row, col, cursor, csr, E);

    int gemmBlocks = (N + 63) / 64;
    int aggBlocks  = (N + 3) / 4;

    // layer 1
    k_gemm_scale<<<gemmBlocks, 256, 0, stream>>>(x, W1, dis, bufA, N);
    k_agg<<<aggBlocks, 256, 0, stream>>>(bufA, csr, offs, dis, b1, bufB, N);
    // layer 2
    k_gemm_scale<<<gemmBlocks, 256, 0, stream>>>(bufB, W2, dis, bufA, N);
    k_agg<<<aggBlocks, 256, 0, stream>>>(bufA, csr, offs, dis, b2, bufB, N);
    // batchnorm
    k_stats<<<512, 128, 0, stream>>>(bufB, sums, N);
    k_bn<<<(N * (D / 4) + 255) / 256, 256, 0, stream>>>(bufB, sums, gamma, beta,
                                                        (float*)d_out, N);
}

// Round 2
// 364.920 us; speedup vs baseline: 1.1942x; 1.1942x over previous
//
#include <hip/hip_runtime.h>

// GCN block: h1 = ReLU(Agg(x@W1)+b1); h2 = ReLU(Agg(h1@W2)+b2); out = BN(h2)
// Agg[n] = dis[n] * ( sum_{e: col=n} h[row_e]*dis[row_e] + h[n]*dis[n] )
// R2: store pre-scaled h rows as bf16 (halves gather bytes: 512->256 B/row),
//     unroll edge loop x4 (4 rows in flight per wave). Accumulate in f32.

#define D 128

__device__ inline float2 bf2x2(unsigned u) {
    float2 r;
    r.x = __uint_as_float(u << 16);
    r.y = __uint_as_float(u & 0xffff0000u);
    return r;
}
__device__ inline unsigned short f2bf(float f) {
    unsigned u = __float_as_uint(f);
    u += 0x7fffu + ((u >> 16) & 1u);   // round-to-nearest-even
    return (unsigned short)(u >> 16);
}

// ---------------- zero scratch ----------------
__global__ void k_zero(int* __restrict__ deg, float* __restrict__ sums, int N) {
    int i = blockIdx.x * blockDim.x + threadIdx.x;
    if (i < N) deg[i] = 0;
    if (i < 256) sums[i] = 0.0f;   // sums[128] ++ sumsq[128]
}

// ---------------- degree histogram ----------------
__global__ void k_hist(const int* __restrict__ col, int* __restrict__ deg, int E) {
    int e = blockIdx.x * blockDim.x + threadIdx.x;
    if (e < E) atomicAdd(&deg[col[e]], 1);
}

// ---------------- prefix scan (3 kernels) ----------------
__global__ void k_scan1(const int* __restrict__ deg, int* __restrict__ bsum, int N) {
    __shared__ int s[256];
    int tid = threadIdx.x;
    int i = blockIdx.x * 256 + tid;
    s[tid] = (i < N) ? deg[i] : 0;
    __syncthreads();
    for (int o = 128; o > 0; o >>= 1) {
        if (tid < o) s[tid] += s[tid + o];
        __syncthreads();
    }
    if (tid == 0) bsum[blockIdx.x] = s[0];
}

__global__ void k_scan2(int* __restrict__ bsum, int nb) {
    __shared__ int s[256];
    int tid = threadIdx.x;
    int v = (tid < nb) ? bsum[tid] : 0;
    s[tid] = v;
    __syncthreads();
    for (int o = 1; o < 256; o <<= 1) {
        int t = (tid >= o) ? s[tid - o] : 0;
        __syncthreads();
        s[tid] += t;
        __syncthreads();
    }
    if (tid < nb) bsum[tid] = tid ? s[tid - 1] : 0;
}

__global__ void k_scan3(const int* __restrict__ deg, const int* __restrict__ bsum,
                        int* __restrict__ offs, int* __restrict__ cursor,
                        float* __restrict__ dis, int N, int E) {
    __shared__ int s[256];
    int tid = threadIdx.x;
    int i = blockIdx.x * 256 + tid;
    int d = (i < N) ? deg[i] : 0;
    s[tid] = d;
    __syncthreads();
    for (int o = 1; o < 256; o <<= 1) {
        int t = (tid >= o) ? s[tid - o] : 0;
        __syncthreads();
        s[tid] += t;
        __syncthreads();
    }
    if (i < N) {
        int excl = (tid ? s[tid - 1] : 0) + bsum[blockIdx.x];
        offs[i] = excl;
        cursor[i] = excl;
        dis[i] = rsqrtf((float)d + 1.0f);
    }
    if (i == 0) offs[N] = E;
}

// ---------------- CSR fill ----------------
__global__ void k_fill(const int* __restrict__ row, const int* __restrict__ col,
                       int* __restrict__ cursor, int* __restrict__ csr, int E) {
    int e = blockIdx.x * blockDim.x + threadIdx.x;
    if (e < E) {
        int p = atomicAdd(&cursor[col[e]], 1);
        csr[p] = row[e];
    }
}

// ---------------- GEMM: hs[r] = bf16( (X @ W)[r] * dis[r] ) ----------------
// Block: 64 rows x 128 cols, 256 threads; thread (ry,cx): 4 rows x 8 cols.
__global__ __launch_bounds__(256) void k_gemm_scale(
        const float* __restrict__ X, const float* __restrict__ W,
        const float* __restrict__ dis, unsigned short* __restrict__ out, int n) {
    __shared__ float Ws[D * D];
    __shared__ float Xt[D * 64];   // transposed: Xt[k*64 + r]
    int tid = threadIdx.x;

    for (int i = tid; i < D * D / 4; i += 256) {
        ((float4*)Ws)[i] = ((const float4*)W)[i];
    }
    int row0 = blockIdx.x * 64;
    for (int i = tid; i < 64 * 32; i += 256) {
        int r = i & 63;
        int kc = (i >> 6) << 2;
        float4 v = {0.f, 0.f, 0.f, 0.f};
        if (row0 + r < n) v = *(const float4*)&X[(size_t)(row0 + r) * D + kc];
        Xt[(kc + 0) * 64 + r] = v.x;
        Xt[(kc + 1) * 64 + r] = v.y;
        Xt[(kc + 2) * 64 + r] = v.z;
        Xt[(kc + 3) * 64 + r] = v.w;
    }
    __syncthreads();

    int ry = tid >> 4;
    int cx = tid & 15;
    float acc[4][8];
#pragma unroll
    for (int i = 0; i < 4; i++)
#pragma unroll
        for (int j = 0; j < 8; j++) acc[i][j] = 0.f;

#pragma unroll 4
    for (int k = 0; k < D; k++) {
        float4 a  = *(const float4*)&Xt[k * 64 + ry * 4];
        float4 b0 = *(const float4*)&Ws[k * D + cx * 4];
        float4 b1 = *(const float4*)&Ws[k * D + 64 + cx * 4];
        float av[4] = {a.x, a.y, a.z, a.w};
        float bv[8] = {b0.x, b0.y, b0.z, b0.w, b1.x, b1.y, b1.z, b1.w};
#pragma unroll
        for (int i = 0; i < 4; i++)
#pragma unroll
            for (int j = 0; j < 8; j++) acc[i][j] += av[i] * bv[j];
    }

#pragma unroll
    for (int i = 0; i < 4; i++) {
        int r = row0 + ry * 4 + i;
        if (r < n) {
            float sc = dis[r];
            ushort4 o0, o1;
            o0.x = f2bf(acc[i][0] * sc); o0.y = f2bf(acc[i][1] * sc);
            o0.z = f2bf(acc[i][2] * sc); o0.w = f2bf(acc[i][3] * sc);
            o1.x = f2bf(acc[i][4] * sc); o1.y = f2bf(acc[i][5] * sc);
            o1.z = f2bf(acc[i][6] * sc); o1.w = f2bf(acc[i][7] * sc);
            *(ushort4*)&out[(size_t)r * D + cx * 4] = o0;
            *(ushort4*)&out[(size_t)r * D + 64 + cx * 4] = o1;
        }
    }
}

// ------- aggregation: y[n] = ReLU(dis[n]*(sum_e hs[src] + hs[n]) + b) -------
// hs rows are bf16, pre-scaled by dis[src]. One wave per node; lane loads
// bf16x2 (4 B) at column 2*lane -> 256 B coalesced per row. Unroll x4 for MLP.
__global__ __launch_bounds__(256) void k_agg(
        const unsigned* __restrict__ hs,   // bf16x2 view, row stride 64 uints
        const int* __restrict__ csr,
        const int* __restrict__ offs, const float* __restrict__ dis,
        const float* __restrict__ bias, float* __restrict__ out, int N) {
    int node = blockIdx.x * 4 + (threadIdx.x >> 6);
    if (node >= N) return;
    int lane = threadIdx.x & 63;

    float2 a0 = bf2x2(hs[(size_t)node * 64 + lane]);  // self term (pre-scaled)
    float2 a1 = {0.f, 0.f}, a2 = {0.f, 0.f}, a3 = {0.f, 0.f};
    int e0 = offs[node], e1 = offs[node + 1];
    int e = e0;
    for (; e + 4 <= e1; e += 4) {
        int s0 = csr[e], s1 = csr[e + 1], s2 = csr[e + 2], s3 = csr[e + 3];
        unsigned u0 = hs[(size_t)s0 * 64 + lane];
        unsigned u1 = hs[(size_t)s1 * 64 + lane];
        unsigned u2 = hs[(size_t)s2 * 64 + lane];
        unsigned u3 = hs[(size_t)s3 * 64 + lane];
        float2 v0 = bf2x2(u0), v1 = bf2x2(u1), v2 = bf2x2(u2), v3 = bf2x2(u3);
        a0.x += v0.x; a0.y += v0.y;
        a1.x += v1.x; a1.y += v1.y;
        a2.x += v2.x; a2.y += v2.y;
        a3.x += v3.x; a3.y += v3.y;
    }
    for (; e < e1; e++) {
        int s = csr[e];
        float2 v = bf2x2(hs[(size_t)s * 64 + lane]);
        a0.x += v.x; a0.y += v.y;
    }
    float accx = (a0.x + a1.x) + (a2.x + a3.x);
    float accy = (a0.y + a1.y) + (a2.y + a3.y);

    float dn = dis[node];
    int c = lane * 2;
    float2 b = *(const float2*)&bias[c];
    float2 o;
    o.x = fmaxf(dn * accx + b.x, 0.0f);
    o.y = fmaxf(dn * accy + b.y, 0.0f);
    *(float2*)&out[(size_t)node * D + c] = o;
}

// ---------------- BN stats ----------------
__global__ void k_stats(const float* __restrict__ z, float* __restrict__ sums, int N) {
    int t = threadIdx.x;
    float s = 0.f, s2 = 0.f;
    for (int n = blockIdx.x; n < N; n += gridDim.x) {
        float v = z[(size_t)n * D + t];
        s += v;
        s2 += v * v;
    }
    atomicAdd(&sums[t], s);
    atomicAdd(&sums[D + t], s2);
}

// ---------------- BN normalize ----------------
__global__ void k_bn(const float* __restrict__ z, const float* __restrict__ sums,
                     const float* __restrict__ gamma, const float* __restrict__ beta,
                     float* __restrict__ out, int N) {
    int i = blockIdx.x * blockDim.x + threadIdx.x;
    int total = N * (D / 4);
    if (i >= total) return;
    int c4 = (i & (D / 4 - 1)) << 2;
    float4 s  = *(const float4*)&sums[c4];
    float4 s2 = *(const float4*)&sums[D + c4];
    float4 g  = *(const float4*)&gamma[c4];
    float4 b  = *(const float4*)&beta[c4];
    float4 v  = *(const float4*)&z[(size_t)i * 4];
    float invN = 1.0f / (float)N;
    float m0 = s.x * invN, m1 = s.y * invN, m2 = s.z * invN, m3 = s.w * invN;
    float i0 = rsqrtf(fmaxf(s2.x * invN - m0 * m0, 0.f) + 1e-5f);
    float i1 = rsqrtf(fmaxf(s2.y * invN - m1 * m1, 0.f) + 1e-5f);
    float i2 = rsqrtf(fmaxf(s2.z * invN - m2 * m2, 0.f) + 1e-5f);
    float i3 = rsqrtf(fmaxf(s2.w * invN - m3 * m3, 0.f) + 1e-5f);
    float4 o;
    o.x = g.x * (v.x - m0) * i0 + b.x;
    o.y = g.y * (v.y - m1) * i1 + b.y;
    o.z = g.z * (v.z - m2) * i2 + b.z;
    o.w = g.w * (v.w - m3) * i3 + b.w;
    *(float4*)&out[(size_t)i * 4] = o;
}

static inline size_t align_up(size_t x) { return (x + 1023) & ~(size_t)1023; }

extern "C" void kernel_launch(void* const* d_in, const int* in_sizes, int n_in,
                              void* d_out, int out_size, void* d_ws, size_t ws_size,
                              hipStream_t stream) {
    const float* x     = (const float*)d_in[0];
    const int*   ei    = (const int*)d_in[1];
    const float* W1    = (const float*)d_in[2];
    const float* b1    = (const float*)d_in[3];
    const float* W2    = (const float*)d_in[4];
    const float* b2    = (const float*)d_in[5];
    const float* gamma = (const float*)d_in[6];
    const float* beta  = (const float*)d_in[7];

    int N = in_sizes[0] / D;
    int E = in_sizes[1] / 2;
    const int* row = ei;
    const int* col = ei + E;

    char* p = (char*)d_ws;
    int* deg    = (int*)p;   p += align_up((size_t)N * 4);
    int* offs   = (int*)p;   p += align_up((size_t)(N + 1) * 4);
    int* cursor = (int*)p;   p += align_up((size_t)N * 4);
    int* bsum   = (int*)p;   p += align_up(256 * 4);
    float* dis  = (float*)p; p += align_up((size_t)N * 4);
    int* csr    = (int*)p;   p += align_up((size_t)E * 4);
    unsigned short* hsb = (unsigned short*)p; p += align_up((size_t)N * D * 2);  // bf16
    float* t1   = (float*)p; p += align_up((size_t)N * D * 4);
    float* t2   = (float*)p; p += align_up((size_t)N * D * 4);
    float* sums = (float*)p; p += align_up(256 * 4);

    int nb = (N + 255) / 256;

    k_zero<<<nb, 256, 0, stream>>>(deg, sums, N);
    k_hist<<<(E + 255) / 256, 256, 0, stream>>>(col, deg, E);
    k_scan1<<<nb, 256, 0, stream>>>(deg, bsum, N);
    k_scan2<<<1, 256, 0, stream>>>(bsum, nb);
    k_scan3<<<nb, 256, 0, stream>>>(deg, bsum, offs, cursor, dis, N, E);
    k_fill<<<(E + 255) / 256, 256, 0, stream>>>(row, col, cursor, csr, E);

    int gemmBlocks = (N + 63) / 64;
    int aggBlocks  = (N + 3) / 4;

    // layer 1
    k_gemm_scale<<<gemmBlocks, 256, 0, stream>>>(x, W1, dis, hsb, N);
    k_agg<<<aggBlocks, 256, 0, stream>>>((const unsigned*)hsb, csr, offs, dis, b1, t1, N);
    // layer 2
    k_gemm_scale<<<gemmBlocks, 256, 0, stream>>>(t1, W2, dis, hsb, N);
    k_agg<<<aggBlocks, 256, 0, stream>>>((const unsigned*)hsb, csr, offs, dis, b2, t2, N);
    // batchnorm
    k_stats<<<512, 128, 0, stream>>>(t2, sums, N);
    k_bn<<<(N * (D / 4) + 255) / 256, 256, 0, stream>>>(t2, sums, gamma, beta,
                                                        (float*)d_out, N);
}

// Round 3
// 291.913 us; speedup vs baseline: 1.4929x; 1.2501x over previous
//
#include <hip/hip_runtime.h>

// GCN block: h1 = ReLU(Agg(x@W1)+b1); h2 = ReLU(Agg(h1@W2)+b2); out = BN(h2)
// R3: bf16 MFMA GEMM (16x16x32), W pre-transposed+converted once, x converted
// once; k_agg emits bf16 for layer1 (next GEMM input) and f32 for layer2 (BN).

#define D 128

typedef __attribute__((ext_vector_type(8))) short bf16x8;
typedef __attribute__((ext_vector_type(4))) float f32x4;

__device__ inline float2 bf2x2(unsigned u) {
    float2 r;
    r.x = __uint_as_float(u << 16);
    r.y = __uint_as_float(u & 0xffff0000u);
    return r;
}
__device__ inline unsigned short f2bf(float f) {
    unsigned u = __float_as_uint(f);
    u += 0x7fffu + ((u >> 16) & 1u);   // round-to-nearest-even
    return (unsigned short)(u >> 16);
}

// ---------------- zero scratch ----------------
__global__ void k_zero(int* __restrict__ deg, float* __restrict__ sums, int N) {
    int i = blockIdx.x * blockDim.x + threadIdx.x;
    if (i < N) deg[i] = 0;
    if (i < 256) sums[i] = 0.0f;
}

// ---------------- degree histogram ----------------
__global__ void k_hist(const int* __restrict__ col, int* __restrict__ deg, int E) {
    int e = blockIdx.x * blockDim.x + threadIdx.x;
    if (e < E) atomicAdd(&deg[col[e]], 1);
}

// ---------------- prefix scan ----------------
__global__ void k_scan1(const int* __restrict__ deg, int* __restrict__ bsum, int N) {
    __shared__ int s[256];
    int tid = threadIdx.x;
    int i = blockIdx.x * 256 + tid;
    s[tid] = (i < N) ? deg[i] : 0;
    __syncthreads();
    for (int o = 128; o > 0; o >>= 1) {
        if (tid < o) s[tid] += s[tid + o];
        __syncthreads();
    }
    if (tid == 0) bsum[blockIdx.x] = s[0];
}

__global__ void k_scan2(int* __restrict__ bsum, int nb) {
    __shared__ int s[256];
    int tid = threadIdx.x;
    int v = (tid < nb) ? bsum[tid] : 0;
    s[tid] = v;
    __syncthreads();
    for (int o = 1; o < 256; o <<= 1) {
        int t = (tid >= o) ? s[tid - o] : 0;
        __syncthreads();
        s[tid] += t;
        __syncthreads();
    }
    if (tid < nb) bsum[tid] = tid ? s[tid - 1] : 0;
}

__global__ void k_scan3(const int* __restrict__ deg, const int* __restrict__ bsum,
                        int* __restrict__ offs, int* __restrict__ cursor,
                        float* __restrict__ dis, int N, int E) {
    __shared__ int s[256];
    int tid = threadIdx.x;
    int i = blockIdx.x * 256 + tid;
    int d = (i < N) ? deg[i] : 0;
    s[tid] = d;
    __syncthreads();
    for (int o = 1; o < 256; o <<= 1) {
        int t = (tid >= o) ? s[tid - o] : 0;
        __syncthreads();
        s[tid] += t;
        __syncthreads();
    }
    if (i < N) {
        int excl = (tid ? s[tid - 1] : 0) + bsum[blockIdx.x];
        offs[i] = excl;
        cursor[i] = excl;
        dis[i] = rsqrtf((float)d + 1.0f);
    }
    if (i == 0) offs[N] = E;
}

// ---------------- CSR fill ----------------
__global__ void k_fill(const int* __restrict__ row, const int* __restrict__ col,
                       int* __restrict__ cursor, int* __restrict__ csr, int E) {
    int e = blockIdx.x * blockDim.x + threadIdx.x;
    if (e < E) {
        int p = atomicAdd(&cursor[col[e]], 1);
        csr[p] = row[e];
    }
}

// ---------------- converters ----------------
// x (f32) -> xb (bf16), 8 elems/thread
__global__ void k_cvt_x(const float* __restrict__ x, unsigned short* __restrict__ xb,
                        int total8) {
    int i = blockIdx.x * blockDim.x + threadIdx.x;
    if (i >= total8) return;
    float4 a = *(const float4*)&x[(size_t)i * 8];
    float4 b = *(const float4*)&x[(size_t)i * 8 + 4];
    ushort4 o0, o1;
    o0.x = f2bf(a.x); o0.y = f2bf(a.y); o0.z = f2bf(a.z); o0.w = f2bf(a.w);
    o1.x = f2bf(b.x); o1.y = f2bf(b.y); o1.z = f2bf(b.z); o1.w = f2bf(b.w);
    *(ushort4*)&xb[(size_t)i * 8] = o0;
    *(ushort4*)&xb[(size_t)i * 8 + 4] = o1;
}

// W[k][n] f32 -> Wt[n][k] bf16, for both weight matrices. grid=128, block=256.
__global__ void k_cvt_w(const float* __restrict__ W1, const float* __restrict__ W2,
                        unsigned short* __restrict__ Wt1, unsigned short* __restrict__ Wt2) {
    int k = blockIdx.x;         // 0..127
    int t = threadIdx.x;        // 0..255
    if (t < D) {
        Wt1[t * D + k] = f2bf(W1[k * D + t]);
    } else {
        int n = t - D;
        Wt2[n * D + k] = f2bf(W2[k * D + n]);
    }
}

// ---------------- MFMA GEMM: out[r] = bf16( (X @ W)[r] * dis[r] ) ----------------
// X: [n][128] bf16 row-major. Wt: [nout][k] bf16 (W transposed).
// Block tile 128x128, 4 waves; wave w: rows w*32..w*32+31 (2 m-tiles), 8 n-tiles.
__global__ __launch_bounds__(256) void k_gemm_mfma(
        const unsigned short* __restrict__ Xb, const unsigned short* __restrict__ Wt,
        const float* __restrict__ dis, unsigned short* __restrict__ out, int n) {
    __shared__ unsigned short Xs[128 * 136];   // +8 pad: 272B stride -> 2-way banks (free)
    __shared__ unsigned short Ws[128 * 136];   // stored [nout][k]
    int tid = threadIdx.x;
    int row0 = blockIdx.x * 128;

    // stage X tile: 128 rows x 16 chunks(16B); 2048 chunks, 8 per thread
#pragma unroll
    for (int i = 0; i < 8; i++) {
        int c = tid + 256 * i;
        int r = c >> 4;
        int kc = (c & 15) * 8;
        uint4 v = {0u, 0u, 0u, 0u};
        if (row0 + r < n) v = *(const uint4*)&Xb[(size_t)(row0 + r) * D + kc];
        *(uint4*)&Xs[r * 136 + kc] = v;
    }
    // stage Wt (always full 128x128)
#pragma unroll
    for (int i = 0; i < 8; i++) {
        int c = tid + 256 * i;
        int r = c >> 4;
        int kc = (c & 15) * 8;
        uint4 v = *(const uint4*)&Wt[r * D + kc];
        *(uint4*)&Ws[r * 136 + kc] = v;
    }
    __syncthreads();

    int w = tid >> 6;
    int lane = tid & 63;
    int m16 = lane & 15;
    int quad = lane >> 4;

    f32x4 acc[2][8];
#pragma unroll
    for (int t = 0; t < 2; t++)
#pragma unroll
        for (int u = 0; u < 8; u++) acc[t][u] = (f32x4){0.f, 0.f, 0.f, 0.f};

#pragma unroll
    for (int kc = 0; kc < 4; kc++) {
        bf16x8 a[2], b[8];
#pragma unroll
        for (int t = 0; t < 2; t++)
            a[t] = *(const bf16x8*)&Xs[(w * 32 + t * 16 + m16) * 136 + kc * 32 + quad * 8];
#pragma unroll
        for (int u = 0; u < 8; u++)
            b[u] = *(const bf16x8*)&Ws[(u * 16 + m16) * 136 + kc * 32 + quad * 8];
#pragma unroll
        for (int t = 0; t < 2; t++)
#pragma unroll
            for (int u = 0; u < 8; u++)
                acc[t][u] = __builtin_amdgcn_mfma_f32_16x16x32_bf16(a[t], b[u], acc[t][u], 0, 0, 0);
    }

    // epilogue: C row = quad*4+i, col = m16 (per m89-verified layout)
#pragma unroll
    for (int t = 0; t < 2; t++) {
        int rbase = row0 + w * 32 + t * 16 + quad * 4;
        float sc[4];
#pragma unroll
        for (int i = 0; i < 4; i++)
            sc[i] = (rbase + i < n) ? dis[rbase + i] : 0.f;
#pragma unroll
        for (int i = 0; i < 4; i++) {
            int r = rbase + i;
            if (r < n) {
#pragma unroll
                for (int u = 0; u < 8; u++)
                    out[(size_t)r * D + u * 16 + m16] = f2bf(acc[t][u][i] * sc[i]);
            }
        }
    }
}

// ------- aggregation: y[n] = ReLU(dis[n]*(sum_e hs[src] + hs[n]) + b) -------
// hs rows bf16 pre-scaled. One wave/node, lane handles 2 cols. Unroll x4.
// BF16OUT: write bf16 (feeds next GEMM); else f32 (feeds BN).
template <bool BF16OUT>
__global__ __launch_bounds__(256) void k_agg(
        const unsigned* __restrict__ hs, const int* __restrict__ csr,
        const int* __restrict__ offs, const float* __restrict__ dis,
        const float* __restrict__ bias,
        unsigned short* __restrict__ out_b, float* __restrict__ out_f, int N) {
    int node = blockIdx.x * 4 + (threadIdx.x >> 6);
    if (node >= N) return;
    int lane = threadIdx.x & 63;

    float2 a0 = bf2x2(hs[(size_t)node * 64 + lane]);
    float2 a1 = {0.f, 0.f}, a2 = {0.f, 0.f}, a3 = {0.f, 0.f};
    int e0 = offs[node], e1 = offs[node + 1];
    int e = e0;
    for (; e + 4 <= e1; e += 4) {
        int s0 = csr[e], s1 = csr[e + 1], s2 = csr[e + 2], s3 = csr[e + 3];
        float2 v0 = bf2x2(hs[(size_t)s0 * 64 + lane]);
        float2 v1 = bf2x2(hs[(size_t)s1 * 64 + lane]);
        float2 v2 = bf2x2(hs[(size_t)s2 * 64 + lane]);
        float2 v3 = bf2x2(hs[(size_t)s3 * 64 + lane]);
        a0.x += v0.x; a0.y += v0.y;
        a1.x += v1.x; a1.y += v1.y;
        a2.x += v2.x; a2.y += v2.y;
        a3.x += v3.x; a3.y += v3.y;
    }
    for (; e < e1; e++) {
        int s = csr[e];
        float2 v = bf2x2(hs[(size_t)s * 64 + lane]);
        a0.x += v.x; a0.y += v.y;
    }
    float accx = (a0.x + a1.x) + (a2.x + a3.x);
    float accy = (a0.y + a1.y) + (a2.y + a3.y);

    float dn = dis[node];
    int c = lane * 2;
    float2 b = *(const float2*)&bias[c];
    float ox = fmaxf(dn * accx + b.x, 0.0f);
    float oy = fmaxf(dn * accy + b.y, 0.0f);
    if (BF16OUT) {
        ushort2 o;
        o.x = f2bf(ox);
        o.y = f2bf(oy);
        *(ushort2*)&out_b[(size_t)node * D + c] = o;
    } else {
        float2 o = {ox, oy};
        *(float2*)&out_f[(size_t)node * D + c] = o;
    }
}

// ---------------- BN stats ----------------
__global__ void k_stats(const float* __restrict__ z, float* __restrict__ sums, int N) {
    int t = threadIdx.x;
    float s = 0.f, s2 = 0.f;
    for (int n = blockIdx.x; n < N; n += gridDim.x) {
        float v = z[(size_t)n * D + t];
        s += v;
        s2 += v * v;
    }
    atomicAdd(&sums[t], s);
    atomicAdd(&sums[D + t], s2);
}

// ---------------- BN normalize ----------------
__global__ void k_bn(const float* __restrict__ z, const float* __restrict__ sums,
                     const float* __restrict__ gamma, const float* __restrict__ beta,
                     float* __restrict__ out, int N) {
    int i = blockIdx.x * blockDim.x + threadIdx.x;
    int total = N * (D / 4);
    if (i >= total) return;
    int c4 = (i & (D / 4 - 1)) << 2;
    float4 s  = *(const float4*)&sums[c4];
    float4 s2 = *(const float4*)&sums[D + c4];
    float4 g  = *(const float4*)&gamma[c4];
    float4 b  = *(const float4*)&beta[c4];
    float4 v  = *(const float4*)&z[(size_t)i * 4];
    float invN = 1.0f / (float)N;
    float m0 = s.x * invN, m1 = s.y * invN, m2 = s.z * invN, m3 = s.w * invN;
    float i0 = rsqrtf(fmaxf(s2.x * invN - m0 * m0, 0.f) + 1e-5f);
    float i1 = rsqrtf(fmaxf(s2.y * invN - m1 * m1, 0.f) + 1e-5f);
    float i2 = rsqrtf(fmaxf(s2.z * invN - m2 * m2, 0.f) + 1e-5f);
    float i3 = rsqrtf(fmaxf(s2.w * invN - m3 * m3, 0.f) + 1e-5f);
    float4 o;
    o.x = g.x * (v.x - m0) * i0 + b.x;
    o.y = g.y * (v.y - m1) * i1 + b.y;
    o.z = g.z * (v.z - m2) * i2 + b.z;
    o.w = g.w * (v.w - m3) * i3 + b.w;
    *(float4*)&out[(size_t)i * 4] = o;
}

static inline size_t align_up(size_t x) { return (x + 1023) & ~(size_t)1023; }

extern "C" void kernel_launch(void* const* d_in, const int* in_sizes, int n_in,
                              void* d_out, int out_size, void* d_ws, size_t ws_size,
                              hipStream_t stream) {
    const float* x     = (const float*)d_in[0];
    const int*   ei    = (const int*)d_in[1];
    const float* W1    = (const float*)d_in[2];
    const float* b1    = (const float*)d_in[3];
    const float* W2    = (const float*)d_in[4];
    const float* b2    = (const float*)d_in[5];
    const float* gamma = (const float*)d_in[6];
    const float* beta  = (const float*)d_in[7];

    int N = in_sizes[0] / D;
    int E = in_sizes[1] / 2;
    const int* row = ei;
    const int* col = ei + E;

    char* p = (char*)d_ws;
    int* deg    = (int*)p;   p += align_up((size_t)N * 4);
    int* offs   = (int*)p;   p += align_up((size_t)(N + 1) * 4);
    int* cursor = (int*)p;   p += align_up((size_t)N * 4);
    int* bsum   = (int*)p;   p += align_up(256 * 4);
    float* dis  = (float*)p; p += align_up((size_t)N * 4);
    int* csr    = (int*)p;   p += align_up((size_t)E * 4);
    unsigned short* xb  = (unsigned short*)p; p += align_up((size_t)N * D * 2);
    unsigned short* hsb = (unsigned short*)p; p += align_up((size_t)N * D * 2);
    unsigned short* h1b = (unsigned short*)p; p += align_up((size_t)N * D * 2);
    float* t2   = (float*)p; p += align_up((size_t)N * D * 4);
    unsigned short* Wt1 = (unsigned short*)p; p += align_up((size_t)D * D * 2);
    unsigned short* Wt2 = (unsigned short*)p; p += align_up((size_t)D * D * 2);
    float* sums = (float*)p; p += align_up(256 * 4);

    int nb = (N + 255) / 256;

    k_zero<<<nb, 256, 0, stream>>>(deg, sums, N);
    k_hist<<<(E + 255) / 256, 256, 0, stream>>>(col, deg, E);
    k_scan1<<<nb, 256, 0, stream>>>(deg, bsum, N);
    k_scan2<<<1, 256, 0, stream>>>(bsum, nb);
    k_scan3<<<nb, 256, 0, stream>>>(deg, bsum, offs, cursor, dis, N, E);
    k_fill<<<(E + 255) / 256, 256, 0, stream>>>(row, col, cursor, csr, E);
    k_cvt_x<<<(N * D / 8 + 255) / 256, 256, 0, stream>>>(x, xb, N * D / 8);
    k_cvt_w<<<D, 256, 0, stream>>>(W1, W2, Wt1, Wt2);

    int gemmBlocks = (N + 127) / 128;
    int aggBlocks  = (N + 3) / 4;

    // layer 1
    k_gemm_mfma<<<gemmBlocks, 256, 0, stream>>>(xb, Wt1, dis, hsb, N);
    k_agg<true><<<aggBlocks, 256, 0, stream>>>((const unsigned*)hsb, csr, offs, dis, b1,
                                               h1b, nullptr, N);
    // layer 2
    k_gemm_mfma<<<gemmBlocks, 256, 0, stream>>>(h1b, Wt2, dis, hsb, N);
    k_agg<false><<<aggBlocks, 256, 0, stream>>>((const unsigned*)hsb, csr, offs, dis, b2,
                                                nullptr, t2, N);
    // batchnorm
    k_stats<<<512, 128, 0, stream>>>(t2, sums, N);
    k_bn<<<(N * (D / 4) + 255) / 256, 256, 0, stream>>>(t2, sums, gamma, beta,
                                                        (float*)d_out, N);
}

// Round 4
// 279.147 us; speedup vs baseline: 1.5612x; 1.0457x over previous
//
#include <hip/hip_runtime.h>

// GCN block: h1 = ReLU(Agg(x@W1)+b1); h2 = ReLU(Agg(h1@W2)+b2); out = BN(h2)
// R4: agg gathers 2 rows/wave-step (uint2 per 32-lane half, 8 rows in flight);
// x->bf16 fused into GEMM1 staging; W-cvt fused into prep; scan2 fused into
// scan3; h2 stored bf16 so stats/bn read half the bytes. 11 launches.

#define D 128

typedef __attribute__((ext_vector_type(8))) short bf16x8;
typedef __attribute__((ext_vector_type(4))) float f32x4;

__device__ inline float2 bf2x2(unsigned u) {
    float2 r;
    r.x = __uint_as_float(u << 16);
    r.y = __uint_as_float(u & 0xffff0000u);
    return r;
}
__device__ inline unsigned short f2bf(float f) {
    unsigned u = __float_as_uint(f);
    u += 0x7fffu + ((u >> 16) & 1u);   // round-to-nearest-even
    return (unsigned short)(u >> 16);
}

// ---------------- prep: zero deg/sums + transpose-convert W1,W2 ----------------
__global__ void k_prep(int* __restrict__ deg, float* __restrict__ sums,
                       const float* __restrict__ W1, const float* __restrict__ W2,
                       unsigned short* __restrict__ Wt1, unsigned short* __restrict__ Wt2,
                       int N) {
    int i = blockIdx.x * blockDim.x + threadIdx.x;
    if (i < N) deg[i] = 0;
    if (i < 256) sums[i] = 0.0f;
    if (blockIdx.x < D) {
        int k = blockIdx.x;
        int t = threadIdx.x;
        if (t < D) Wt1[t * D + k] = f2bf(W1[k * D + t]);
        else       Wt2[(t - D) * D + k] = f2bf(W2[k * D + (t - D)]);
    }
}

// ---------------- degree histogram ----------------
__global__ void k_hist(const int* __restrict__ col, int* __restrict__ deg, int E) {
    int e = blockIdx.x * blockDim.x + threadIdx.x;
    if (e < E) atomicAdd(&deg[col[e]], 1);
}

// ---------------- scan stage 1: per-block sums ----------------
__global__ void k_scan1(const int* __restrict__ deg, int* __restrict__ bsum, int N) {
    __shared__ int s[256];
    int tid = threadIdx.x;
    int i = blockIdx.x * 256 + tid;
    s[tid] = (i < N) ? deg[i] : 0;
    __syncthreads();
    for (int o = 128; o > 0; o >>= 1) {
        if (tid < o) s[tid] += s[tid + o];
        __syncthreads();
    }
    if (tid == 0) bsum[blockIdx.x] = s[0];
}

// ---------------- scan stage 2: block-local scan + own-prefix reduce ----------------
__global__ void k_scan3(const int* __restrict__ deg, const int* __restrict__ bsum,
                        int* __restrict__ offs, int* __restrict__ cursor,
                        float* __restrict__ dis, int N, int E) {
    __shared__ int s[256];
    __shared__ int sb[256];
    int tid = threadIdx.x;
    int i = blockIdx.x * 256 + tid;
    // base = sum of bsum[0..blockIdx-1]  (gridDim.x <= 256)
    sb[tid] = (tid < blockIdx.x) ? bsum[tid] : 0;
    int d = (i < N) ? deg[i] : 0;
    s[tid] = d;
    __syncthreads();
    for (int o = 128; o > 0; o >>= 1) {
        if (tid < o) sb[tid] += sb[tid + o];
        __syncthreads();
    }
    int base = sb[0];
    __syncthreads();
    for (int o = 1; o < 256; o <<= 1) {
        int t = (tid >= o) ? s[tid - o] : 0;
        __syncthreads();
        s[tid] += t;
        __syncthreads();
    }
    if (i < N) {
        int excl = (tid ? s[tid - 1] : 0) + base;
        offs[i] = excl;
        cursor[i] = excl;
        dis[i] = rsqrtf((float)d + 1.0f);
    }
    if (i == 0) offs[N] = E;
}

// ---------------- CSR fill ----------------
__global__ void k_fill(const int* __restrict__ row, const int* __restrict__ col,
                       int* __restrict__ cursor, int* __restrict__ csr, int E) {
    int e = blockIdx.x * blockDim.x + threadIdx.x;
    if (e < E) {
        int p = atomicAdd(&cursor[col[e]], 1);
        csr[p] = row[e];
    }
}

// ---------------- MFMA GEMM: out[r] = bf16( (X @ W)[r] * dis[r] ) ----------------
// F32IN: X is f32 (converted during staging); else bf16. Wt: [nout][k] bf16.
// Block tile 128x128, 4 waves; wave w: 2 m-tiles, 8 n-tiles, 16x16x32 MFMA.
template <bool F32IN>
__global__ __launch_bounds__(256) void k_gemm_mfma(
        const void* __restrict__ Xin, const unsigned short* __restrict__ Wt,
        const float* __restrict__ dis, unsigned short* __restrict__ out, int n) {
    __shared__ unsigned short Xs[128 * 136];   // +8 pad: 272B stride, 2-way banks (free)
    __shared__ unsigned short Ws[128 * 136];
    int tid = threadIdx.x;
    int row0 = blockIdx.x * 128;

#pragma unroll
    for (int i = 0; i < 8; i++) {
        int c = tid + 256 * i;
        int r = c >> 4;
        int kc = (c & 15) * 8;
        if (F32IN) {
            const float* Xf = (const float*)Xin;
            float4 va = {0.f, 0.f, 0.f, 0.f}, vb = {0.f, 0.f, 0.f, 0.f};
            if (row0 + r < n) {
                va = *(const float4*)&Xf[(size_t)(row0 + r) * D + kc];
                vb = *(const float4*)&Xf[(size_t)(row0 + r) * D + kc + 4];
            }
            ushort4 o0, o1;
            o0.x = f2bf(va.x); o0.y = f2bf(va.y); o0.z = f2bf(va.z); o0.w = f2bf(va.w);
            o1.x = f2bf(vb.x); o1.y = f2bf(vb.y); o1.z = f2bf(vb.z); o1.w = f2bf(vb.w);
            *(ushort4*)&Xs[r * 136 + kc] = o0;
            *(ushort4*)&Xs[r * 136 + kc + 4] = o1;
        } else {
            const unsigned short* Xb = (const unsigned short*)Xin;
            uint4 v = {0u, 0u, 0u, 0u};
            if (row0 + r < n) v = *(const uint4*)&Xb[(size_t)(row0 + r) * D + kc];
            *(uint4*)&Xs[r * 136 + kc] = v;
        }
    }
#pragma unroll
    for (int i = 0; i < 8; i++) {
        int c = tid + 256 * i;
        int r = c >> 4;
        int kc = (c & 15) * 8;
        uint4 v = *(const uint4*)&Wt[r * D + kc];
        *(uint4*)&Ws[r * 136 + kc] = v;
    }
    __syncthreads();

    int w = tid >> 6;
    int lane = tid & 63;
    int m16 = lane & 15;
    int quad = lane >> 4;

    f32x4 acc[2][8];
#pragma unroll
    for (int t = 0; t < 2; t++)
#pragma unroll
        for (int u = 0; u < 8; u++) acc[t][u] = (f32x4){0.f, 0.f, 0.f, 0.f};

#pragma unroll
    for (int kc = 0; kc < 4; kc++) {
        bf16x8 a[2], b[8];
#pragma unroll
        for (int t = 0; t < 2; t++)
            a[t] = *(const bf16x8*)&Xs[(w * 32 + t * 16 + m16) * 136 + kc * 32 + quad * 8];
#pragma unroll
        for (int u = 0; u < 8; u++)
            b[u] = *(const bf16x8*)&Ws[(u * 16 + m16) * 136 + kc * 32 + quad * 8];
#pragma unroll
        for (int t = 0; t < 2; t++)
#pragma unroll
            for (int u = 0; u < 8; u++)
                acc[t][u] = __builtin_amdgcn_mfma_f32_16x16x32_bf16(a[t], b[u], acc[t][u], 0, 0, 0);
    }

    // epilogue: C row = quad*4+i, col = m16
#pragma unroll
    for (int t = 0; t < 2; t++) {
        int rbase = row0 + w * 32 + t * 16 + quad * 4;
#pragma unroll
        for (int i = 0; i < 4; i++) {
            int r = rbase + i;
            if (r < n) {
                float sc = dis[r];
#pragma unroll
                for (int u = 0; u < 8; u++)
                    out[(size_t)r * D + u * 16 + m16] = f2bf(acc[t][u][i] * sc);
            }
        }
    }
}

// ------- aggregation: y[n] = bf16(ReLU(dis[n]*(sum_e hs[src] + hs[n]) + b)) -------
// One wave per node. Lane half h (32 lanes) gathers edges e0+h, e0+h+2, ...
// Each half-lane reads uint2 (8B = 4 bf16 features at 4*l32). Unroll x4 ->
// 8 rows in flight per wave. Halves combined by shfl_xor(32) at the end.
__global__ __launch_bounds__(256) void k_agg(
        const uint2* __restrict__ hs2,     // bf16 rows, stride 32 uint2
        const int* __restrict__ csr,
        const int* __restrict__ offs, const float* __restrict__ dis,
        const float* __restrict__ bias, unsigned short* __restrict__ out, int N) {
    int node = blockIdx.x * 4 + (threadIdx.x >> 6);
    if (node >= N) return;
    int lane = threadIdx.x & 63;
    int half = lane >> 5;
    int l32 = lane & 31;

    float p0 = 0.f, p1 = 0.f, p2 = 0.f, p3 = 0.f;   // partial set A
    float q0 = 0.f, q1 = 0.f, q2 = 0.f, q3 = 0.f;   // partial set B
    if (half == 0) {  // self term (pre-scaled) on half 0 only
        uint2 u = hs2[(size_t)node * 32 + l32];
        float2 v0 = bf2x2(u.x), v1 = bf2x2(u.y);
        p0 = v0.x; p1 = v0.y; p2 = v1.x; p3 = v1.y;
    }

    int e0 = offs[node], e1 = offs[node + 1];
    int m = e1 - e0;
    int cnt = (m - half + 1) >> 1;          // edges this half owns
    const int* cp = csr + e0 + half;
    int k = 0;
    for (; k + 4 <= cnt; k += 4) {
        int s0 = cp[2 * k], s1 = cp[2 * k + 2], s2 = cp[2 * k + 4], s3 = cp[2 * k + 6];
        uint2 u0 = hs2[(size_t)s0 * 32 + l32];
        uint2 u1 = hs2[(size_t)s1 * 32 + l32];
        uint2 u2 = hs2[(size_t)s2 * 32 + l32];
        uint2 u3 = hs2[(size_t)s3 * 32 + l32];
        float2 a0 = bf2x2(u0.x), a1 = bf2x2(u0.y);
        float2 b0 = bf2x2(u1.x), b1 = bf2x2(u1.y);
        float2 c0 = bf2x2(u2.x), c1 = bf2x2(u2.y);
        float2 d0 = bf2x2(u3.x), d1 = bf2x2(u3.y);
        p0 += a0.x; p1 += a0.y; p2 += a1.x; p3 += a1.y;
        q0 += b0.x; q1 += b0.y; q2 += b1.x; q3 += b1.y;
        p0 += c0.x; p1 += c0.y; p2 += c1.x; p3 += c1.y;
        q0 += d0.x; q1 += d0.y; q2 += d1.x; q3 += d1.y;
    }
    for (; k < cnt; k++) {
        int s = cp[2 * k];
        uint2 u = hs2[(size_t)s * 32 + l32];
        float2 v0 = bf2x2(u.x), v1 = bf2x2(u.y);
        p0 += v0.x; p1 += v0.y; p2 += v1.x; p3 += v1.y;
    }
    float a0 = p0 + q0, a1 = p1 + q1, a2 = p2 + q2, a3 = p3 + q3;
    a0 += __shfl_xor(a0, 32);
    a1 += __shfl_xor(a1, 32);
    a2 += __shfl_xor(a2, 32);
    a3 += __shfl_xor(a3, 32);

    if (half == 0) {
        float dn = dis[node];
        float4 b = *(const float4*)&bias[4 * l32];
        ushort4 o;
        o.x = f2bf(fmaxf(dn * a0 + b.x, 0.0f));
        o.y = f2bf(fmaxf(dn * a1 + b.y, 0.0f));
        o.z = f2bf(fmaxf(dn * a2 + b.z, 0.0f));
        o.w = f2bf(fmaxf(dn * a3 + b.w, 0.0f));
        *(ushort4*)&out[(size_t)node * D + 4 * l32] = o;
    }
}

// ---------------- BN stats from bf16 h2 ----------------
__global__ __launch_bounds__(256) void k_stats(const unsigned* __restrict__ z2,
                                               float* __restrict__ sums, int N) {
    int tid = threadIdx.x;
    int fp = tid & 63;      // feature pair: features 2fp, 2fp+1
    int g = tid >> 6;       // wave id 0..3
    float s0 = 0.f, s1 = 0.f, q0 = 0.f, q1 = 0.f;
    for (int n = blockIdx.x * 4 + g; n < N; n += gridDim.x * 4) {
        float2 v = bf2x2(z2[(size_t)n * 64 + fp]);
        s0 += v.x; s1 += v.y;
        q0 += v.x * v.x; q1 += v.y * v.y;
    }
    __shared__ float sm[256][4];
    sm[tid][0] = s0; sm[tid][1] = s1; sm[tid][2] = q0; sm[tid][3] = q1;
    __syncthreads();
    if (tid < 64) {
#pragma unroll
        for (int gg = 1; gg < 4; gg++) {
            s0 += sm[tid + 64 * gg][0];
            s1 += sm[tid + 64 * gg][1];
            q0 += sm[tid + 64 * gg][2];
            q1 += sm[tid + 64 * gg][3];
        }
        atomicAdd(&sums[2 * tid], s0);
        atomicAdd(&sums[2 * tid + 1], s1);
        atomicAdd(&sums[D + 2 * tid], q0);
        atomicAdd(&sums[D + 2 * tid + 1], q1);
    }
}

// ---------------- BN normalize: bf16 h2 -> f32 out ----------------
__global__ void k_bn(const unsigned* __restrict__ z2, const float* __restrict__ sums,
                     const float* __restrict__ gamma, const float* __restrict__ beta,
                     float* __restrict__ out, int N) {
    int i = blockIdx.x * blockDim.x + threadIdx.x;   // uint4 index (8 features)
    int total = N * (D / 8);
    if (i >= total) return;
    int c8 = (i & (D / 8 - 1)) * 8;
    uint4 u = *(const uint4*)&z2[(size_t)i * 4];
    float v[8];
    float2 t;
    t = bf2x2(u.x); v[0] = t.x; v[1] = t.y;
    t = bf2x2(u.y); v[2] = t.x; v[3] = t.y;
    t = bf2x2(u.z); v[4] = t.x; v[5] = t.y;
    t = bf2x2(u.w); v[6] = t.x; v[7] = t.y;
    float invN = 1.0f / (float)N;
    float4 o0, o1;
    float* op = &o0.x;
#pragma unroll
    for (int j = 0; j < 8; j++) {
        float s = sums[c8 + j];
        float s2 = sums[D + c8 + j];
        float mu = s * invN;
        float iv = rsqrtf(fmaxf(s2 * invN - mu * mu, 0.f) + 1e-5f);
        float val = gamma[c8 + j] * (v[j] - mu) * iv + beta[c8 + j];
        if (j < 4) (&o0.x)[j] = val; else (&o1.x)[j - 4] = val;
    }
    (void)op;
    size_t base = (size_t)i * 8;
    *(float4*)&out[base] = o0;
    *(float4*)&out[base + 4] = o1;
}

static inline size_t align_up(size_t x) { return (x + 1023) & ~(size_t)1023; }

extern "C" void kernel_launch(void* const* d_in, const int* in_sizes, int n_in,
                              void* d_out, int out_size, void* d_ws, size_t ws_size,
                              hipStream_t stream) {
    const float* x     = (const float*)d_in[0];
    const int*   ei    = (const int*)d_in[1];
    const float* W1    = (const float*)d_in[2];
    const float* b1    = (const float*)d_in[3];
    const float* W2    = (const float*)d_in[4];
    const float* b2    = (const float*)d_in[5];
    const float* gamma = (const float*)d_in[6];
    const float* beta  = (const float*)d_in[7];

    int N = in_sizes[0] / D;
    int E = in_sizes[1] / 2;
    const int* row = ei;
    const int* col = ei + E;

    char* p = (char*)d_ws;
    int* deg    = (int*)p;   p += align_up((size_t)N * 4);
    int* offs   = (int*)p;   p += align_up((size_t)(N + 1) * 4);
    int* cursor = (int*)p;   p += align_up((size_t)N * 4);
    int* bsum   = (int*)p;   p += align_up(256 * 4);
    float* dis  = (float*)p; p += align_up((size_t)N * 4);
    int* csr    = (int*)p;   p += align_up((size_t)E * 4);
    unsigned short* hsb = (unsigned short*)p; p += align_up((size_t)N * D * 2);
    unsigned short* h1b = (unsigned short*)p; p += align_up((size_t)N * D * 2);
    unsigned short* h2b = (unsigned short*)p; p += align_up((size_t)N * D * 2);
    unsigned short* Wt1 = (unsigned short*)p; p += align_up((size_t)D * D * 2);
    unsigned short* Wt2 = (unsigned short*)p; p += align_up((size_t)D * D * 2);
    float* sums = (float*)p; p += align_up(256 * 4);

    int nb = (N + 255) / 256;   // 196 <= 256

    k_prep<<<nb, 256, 0, stream>>>(deg, sums, W1, W2, Wt1, Wt2, N);
    k_hist<<<(E + 255) / 256, 256, 0, stream>>>(col, deg, E);
    k_scan1<<<nb, 256, 0, stream>>>(deg, bsum, N);
    k_scan3<<<nb, 256, 0, stream>>>(deg, bsum, offs, cursor, dis, N, E);
    k_fill<<<(E + 255) / 256, 256, 0, stream>>>(row, col, cursor, csr, E);

    int gemmBlocks = (N + 127) / 128;
    int aggBlocks  = (N + 3) / 4;

    // layer 1
    k_gemm_mfma<true><<<gemmBlocks, 256, 0, stream>>>(x, Wt1, dis, hsb, N);
    k_agg<<<aggBlocks, 256, 0, stream>>>((const uint2*)hsb, csr, offs, dis, b1, h1b, N);
    // layer 2
    k_gemm_mfma<false><<<gemmBlocks, 256, 0, stream>>>(h1b, Wt2, dis, hsb, N);
    k_agg<<<aggBlocks, 256, 0, stream>>>((const uint2*)hsb, csr, offs, dis, b2, h2b, N);
    // batchnorm
    k_stats<<<512, 256, 0, stream>>>((const unsigned*)h2b, sums, N);
    k_bn<<<(N * (D / 8) + 255) / 256, 256, 0, stream>>>((const unsigned*)h2b, sums,
                                                        gamma, beta, (float*)d_out, N);
}